// Round 8
// baseline (461.457 us; speedup 1.0000x reference)
//
#include <hip/hip_runtime.h>
#include <hip/hip_bf16.h>

#define LJ 256008       // T*BANDS
#define TN 32001
#define OUT_LEN 32000

// ---------------- h1 = relu(x @ lstm_W1 + b1), stored [i][b] (f32) ----------------
__global__ __launch_bounds__(256) void k_h1(const float* __restrict__ x,
                                            const float* __restrict__ W1,
                                            const float* __restrict__ b1,
                                            float* __restrict__ h1)
{
    int idx = blockIdx.x * 256 + threadIdx.x;   // 4096 outputs
    if (idx >= 4096) return;
    int b = idx >> 6, i = idx & 63;
    float acc = b1[i];
    #pragma unroll
    for (int f = 0; f < 16; ++f)
        acc += x[b * 16 + f] * W1[f * 64 + i];
    h1[i * 64 + b] = fmaxf(acc, 0.f);
}

// -------- big GEMM: edc_pred = h1 @ W2 + b2 (f32 out) + fused exact-f32 band-mean -> edc1d ----
__global__ __launch_bounds__(256) void k_gemm(const float* __restrict__ W2,
                                              const float* __restrict__ b2,
                                              const float* __restrict__ h1,
                                              float* __restrict__ edc,
                                              float* __restrict__ edc1d)
{
    __shared__ float h1s[4096];
    int tid = threadIdx.x;
    for (int r = tid; r < 4096; r += 256) h1s[r] = h1[r];
    __syncthreads();
    int lane = tid & 63, bg = tid >> 6;          // wave-uniform bg
    long jb = (long)blockIdx.x * 256 + lane;     // this thread's columns: jb + 64*c
    float acc[4][16];
    #pragma unroll
    for (int c = 0; c < 4; ++c)
        #pragma unroll
        for (int b = 0; b < 16; ++b) acc[c][b] = 0.f;
    bool a0 = jb < LJ, a1 = jb + 64 < LJ, a2 = jb + 128 < LJ, a3 = jb + 192 < LJ;
    for (int i = 0; i < 64; ++i) {
        const float* wr = W2 + (long)i * LJ + jb;
        float w0 = a0 ? wr[0]   : 0.f;
        float w1 = a1 ? wr[64]  : 0.f;
        float w2 = a2 ? wr[128] : 0.f;
        float w3 = a3 ? wr[192] : 0.f;
        const float4* hv = (const float4*)(h1s + i * 64 + bg * 16);
        #pragma unroll
        for (int b4 = 0; b4 < 4; ++b4) {
            float4 h4 = hv[b4];
            acc[0][b4*4+0] += h4.x * w0; acc[0][b4*4+1] += h4.y * w0;
            acc[0][b4*4+2] += h4.z * w0; acc[0][b4*4+3] += h4.w * w0;
            acc[1][b4*4+0] += h4.x * w1; acc[1][b4*4+1] += h4.y * w1;
            acc[1][b4*4+2] += h4.z * w1; acc[1][b4*4+3] += h4.w * w1;
            acc[2][b4*4+0] += h4.x * w2; acc[2][b4*4+1] += h4.y * w2;
            acc[2][b4*4+2] += h4.z * w2; acc[2][b4*4+3] += h4.w * w2;
            acc[3][b4*4+0] += h4.x * w3; acc[3][b4*4+1] += h4.y * w3;
            acc[3][b4*4+2] += h4.z * w3; acc[3][b4*4+3] += h4.w * w3;
        }
    }
    int bgbase = bg * 16;
    #pragma unroll
    for (int c = 0; c < 4; ++c) {
        long j = jb + 64 * c;
        if (j < LJ) {               // 8-lane groups never split here (LJ % 8 == 0)
            float bias = b2[j];
            int t = (int)(j >> 3), band = (int)(j & 7);
            #pragma unroll
            for (int b = 0; b < 16; ++b) {
                float v = acc[c][b] + bias;
                edc[(long)(bgbase + b) * LJ + j] = v;
                float s = v;
                s += __shfl_xor(s, 1);
                s += __shfl_xor(s, 2);
                s += __shfl_xor(s, 4);
                if (band == 0) edc1d[(long)(bgbase + b) * TN + t] = s * 0.125f;
            }
        }
    }
}

// ---------------- time/quartile means of edc_pred -> sums[b][band][{all,q1,q4}] ----------------
__global__ __launch_bounds__(256) void k_reduce(const float* __restrict__ edc,
                                                float* __restrict__ sums)
{
    int b = blockIdx.x, c = blockIdx.y, tid = threadIdx.x;
    float sA = 0.f, s1 = 0.f, s4 = 0.f;
    for (int it = 0; it < 32; ++it) {
        int jl = c * 8192 + tid + it * 256;           // band = tid&7 invariant
        if (jl < LJ) {
            float v = edc[(long)b * LJ + jl];
            int t = jl >> 3;
            sA += v;
            if (t < 8000) s1 += v;
            if (t >= 24000) s4 += v;
        }
    }
    __shared__ float red[768];
    red[tid] = sA; red[tid + 256] = s1; red[tid + 512] = s4;
    __syncthreads();
    #pragma unroll
    for (int off = 128; off >= 8; off >>= 1) {
        if (tid < off) {
            red[tid] += red[tid + off];
            red[tid + 256] += red[tid + 256 + off];
            red[tid + 512] += red[tid + 512 + off];
        }
        __syncthreads();
    }
    if (tid < 8) {
        atomicAdd(&sums[b * 24 + tid * 3 + 0], red[tid]);
        atomicAdd(&sums[b * 24 + tid * 3 + 1], red[tid + 256]);
        atomicAdd(&sums[b * 24 + tid * 3 + 2], red[tid + 512]);
    }
}

// ---------------- small MLP head: one block per batch row, f32 outputs ----------------
__global__ __launch_bounds__(64) void k_mlp(const float* __restrict__ x,
    const float* __restrict__ sums,
    const float* __restrict__ eW1, const float* __restrict__ eb1,
    const float* __restrict__ eW2, const float* __restrict__ eb2,
    const float* __restrict__ dW1, const float* __restrict__ db1,
    const float* __restrict__ dW2, const float* __restrict__ db2,
    const float* __restrict__ aW1, const float* __restrict__ ab1,
    const float* __restrict__ aW2, const float* __restrict__ ab2,
    const float* __restrict__ bW1, const float* __restrict__ bb1,
    const float* __restrict__ bW2, const float* __restrict__ bb2,
    float* __restrict__ out_lk, float* __restrict__ out_a, float* __restrict__ out_b)
{
    int b = blockIdx.x, o = threadIdx.x;
    __shared__ float feat[16], a1[64], hh[64], t1[64];
    if (o < 16) {
        float v;
        if (o < 8) v = sums[b * 24 + o * 3] * (1.f / 32001.f);
        else {
            int band = o - 8;
            v = sums[b * 24 + band * 3 + 2] * (1.f / 8001.f)
              - sums[b * 24 + band * 3 + 1] * (1.f / 8000.f);
        }
        feat[o] = v;
    }
    __syncthreads();
    {   float acc = eb1[o];
        #pragma unroll
        for (int c = 0; c < 16; ++c) acc += feat[c] * eW1[c * 64 + o];
        a1[o] = fmaxf(acc, 0.f); }
    __syncthreads();
    {   float acc = eb2[o];
        for (int c = 0; c < 64; ++c) acc += a1[c] * eW2[c * 64 + o];
        hh[o] = fmaxf(acc, 0.f); }
    __syncthreads();
    {   float acc = db1[o];
        #pragma unroll
        for (int c = 0; c < 3; ++c) acc += x[b * 16 + c] * dW1[c * 64 + o];
        for (int c = 0; c < 64; ++c) acc += hh[c] * dW1[(3 + c) * 64 + o];
        t1[o] = fmaxf(acc, 0.f); }
    __syncthreads();
    if (o < 16) {
        float acc = db2[o];
        for (int c = 0; c < 64; ++c) acc += t1[c] * dW2[c * 16 + o];
        out_lk[b * 16 + o] = acc;
    }
    __syncthreads();
    if (o < 32) {
        float acc = ab1[o];
        for (int c = 0; c < 64; ++c) acc += hh[c] * aW1[c * 32 + o];
        t1[o] = fmaxf(acc, 0.f);
    }
    __syncthreads();
    if (o < 16) {
        float acc = ab2[o];
        for (int c = 0; c < 32; ++c) acc += t1[c] * aW2[c * 16 + o];
        out_a[b * 16 + o] = acc;
    }
    __syncthreads();
    if (o < 32) {
        float acc = bb1[o];
        for (int c = 0; c < 64; ++c) acc += hh[c] * bW1[c * 32 + o];
        t1[o] = fmaxf(acc, 0.f);
    }
    __syncthreads();
    if (o < 16) {
        float acc = bb2[o];
        for (int c = 0; c < 32; ++c) acc += t1[c] * bW2[c * 16 + o];
        out_b[b * 16 + o] = acc;
    }
}

// ---------------- parity stage 1: packed bits (per-(b, 256-chunk) inclusive XOR scan) ----------
__global__ __launch_bounds__(256) void k_par1(const int* __restrict__ flips,
                                              unsigned* __restrict__ parbits,
                                              unsigned* __restrict__ ctot)
{
    int b = blockIdx.x, c = blockIdx.y, tid = threadIdx.x;
    int t = c * 256 + tid;
    int bit = (t == 0) ? 0 : (flips[(long)b * OUT_LEN + t] & 1);
    int lane = tid & 63, wv = tid >> 6;
    unsigned long long mask = __ballot(bit != 0);
    int below = ((int)__popcll(mask & ((1ull << lane) - 1ull))) & 1;
    int incl = below ^ bit;
    __shared__ int wtot[4];
    if (lane == 0) wtot[wv] = ((int)__popcll(mask)) & 1;
    __syncthreads();
    int pre = 0;
    for (int w = 0; w < wv; ++w) pre ^= wtot[w];
    int inclB = pre ^ incl;
    unsigned long long m2 = __ballot(inclB != 0);
    if (lane == 0)  parbits[b * 1000 + c * 8 + wv * 2 + 0] = (unsigned)(m2 & 0xffffffffull);
    if (lane == 32) parbits[b * 1000 + c * 8 + wv * 2 + 1] = (unsigned)(m2 >> 32);
    if (tid == 0) ctot[c * 64 + b] = (unsigned)(wtot[0] ^ wtot[1] ^ wtot[2] ^ wtot[3]);
}

// ---------------- parity stage 2: exclusive prefix over chunks ----------------
__global__ __launch_bounds__(64) void k_par2(const unsigned* __restrict__ ctot,
                                             unsigned* __restrict__ cpref)
{
    int b = threadIdx.x;
    unsigned carry = 0;
    for (int c = 0; c < 125; ++c) {
        cpref[c * 64 + b] = carry;
        carry ^= ctot[c * 64 + b];
    }
}

// ---------------- combined causal conv (late+early) + amp + sign -> rir (f32 out) ----------
__global__ __launch_bounds__(256) void k_conv(const float* __restrict__ edc1d,
    const float* __restrict__ lk, const float* __restrict__ eg,
    const unsigned* __restrict__ parbits, const unsigned* __restrict__ cpref,
    float* __restrict__ rir)
{
    __shared__ __align__(16) float ker[1024];
    __shared__ __align__(16) float sw[5128];
    int b = blockIdx.x, t0 = blockIdx.y * 4096, tid = threadIdx.x;
    for (int k = tid; k < 1024; k += 256) {
        float g = lk[k];
        if (k < 43) g += eg[k];                   // early+late = one conv
        ker[k] = g;
    }
    const float* src = edc1d + (long)b * TN;
    for (int u = tid; u < 5121; u += 256) {
        int gt = t0 - 1024 + u;
        sw[u] = (gt >= 0 && gt <= OUT_LEN) ? src[gt] : 0.f;
    }
    __syncthreads();
    int lt = tid * 16;
    int t = t0 + lt;
    if (t >= OUT_LEN) return;
    float acc[16];
    #pragma unroll
    for (int d = 0; d < 16; ++d) acc[d] = 0.f;
    for (int k8 = 0; k8 < 1024; k8 += 8) {
        const float4* gp = (const float4*)(ker + k8);
        float4 gA = gp[0], gB = gp[1];
        float g[8] = {gA.x, gA.y, gA.z, gA.w, gB.x, gB.y, gB.z, gB.w};
        const float4* sp = (const float4*)(sw + (lt + 1024 - k8 - 8));
        float4 s0 = sp[0], s1 = sp[1], s2 = sp[2], s3 = sp[3], s4 = sp[4], s5 = sp[5];
        float w[24] = {s0.x,s0.y,s0.z,s0.w, s1.x,s1.y,s1.z,s1.w, s2.x,s2.y,s2.z,s2.w,
                       s3.x,s3.y,s3.z,s3.w, s4.x,s4.y,s4.z,s4.w, s5.x,s5.y,s5.z,s5.w};
        #pragma unroll
        for (int j = 0; j < 8; ++j)
            #pragma unroll
            for (int d = 0; d < 16; ++d)
                acc[d] += g[j] * w[d - j + 8];   // w[m] = src[t + m - 8 - k8]
    }
    unsigned pw = parbits[b * 1000 + (t >> 5)];   // all 16 t share one word (t%32 in {0,16})
    unsigned cp = cpref[(t >> 8) * 64 + b] & 1u;
    int sh = t & 31;
    float r[16];
    #pragma unroll
    for (int d = 0; d < 16; ++d) {
        float diff = sw[lt + 1024 + d] - sw[lt + 1024 + d + 1];
        float amp = diff > 0.f ? sqrtf(diff) : 0.f;
        unsigned p = ((pw >> (sh + d)) & 1u) ^ cp;
        float sgn = p ? -1.f : 1.f;
        r[d] = acc[d] * amp * sgn;
    }
    float4* dst = (float4*)(rir + (long)b * OUT_LEN + t);
    dst[0] = make_float4(r[0],  r[1],  r[2],  r[3]);
    dst[1] = make_float4(r[4],  r[5],  r[6],  r[7]);
    dst[2] = make_float4(r[8],  r[9],  r[10], r[11]);
    dst[3] = make_float4(r[12], r[13], r[14], r[15]);
}

extern "C" void kernel_launch(void* const* d_in, const int* in_sizes, int n_in,
                              void* d_out, int out_size, void* d_ws, size_t ws_size,
                              hipStream_t stream) {
    (void)in_sizes; (void)n_in; (void)out_size; (void)ws_size;
    const float* x    = (const float*)d_in[0];
    const float* lW1  = (const float*)d_in[1];  const float* lb1 = (const float*)d_in[2];
    const float* lW2  = (const float*)d_in[3];  const float* lb2 = (const float*)d_in[4];
    const float* eW1  = (const float*)d_in[5];  const float* eb1 = (const float*)d_in[6];
    const float* eW2  = (const float*)d_in[7];  const float* eb2 = (const float*)d_in[8];
    const float* dW1  = (const float*)d_in[9];  const float* db1 = (const float*)d_in[10];
    const float* dW2  = (const float*)d_in[11]; const float* db2 = (const float*)d_in[12];
    const float* aW1  = (const float*)d_in[13]; const float* ab1 = (const float*)d_in[14];
    const float* aW2  = (const float*)d_in[15]; const float* ab2 = (const float*)d_in[16];
    const float* bW1  = (const float*)d_in[17]; const float* bb1 = (const float*)d_in[18];
    const float* bW2  = (const float*)d_in[19]; const float* bb2 = (const float*)d_in[20];
    const float* eg   = (const float*)d_in[21]; const float* lkk = (const float*)d_in[22];
    const int* flips  = (const int*)d_in[23];

    float* out = (float*)d_out;                    // *** f32 output buffer ***
    float* rir = out;                              // 2,048,000
    float* edc = out + 2048000;                    // 16,384,512
    float* olk = out + 18432512;                   // 1,024
    float* oa  = out + 18433536;                   // 1,024
    float* ob  = out + 18434560;                   // 16 x 64

    // -------- compact ws layout (total 8,538,368 B) --------
    char* wsb = (char*)d_ws;
    float*    ws_h1   = (float*)(wsb + 1024);       // 16,384 B
    unsigned* ws_ct   = (unsigned*)(wsb + 18432);   // 32,000 B
    unsigned* ws_cp   = (unsigned*)(wsb + 50688);   // 32,000 B
    unsigned* ws_pb   = (unsigned*)(wsb + 82944);   // 256,000 B
    float*    ws_sums = (float*)(wsb + 339200);     // 6,144 B
    float*    ws_e1d  = (float*)(wsb + 346112);     // 8,192,256 B -> ends 8,538,368

    hipMemsetAsync(ws_sums, 0, 64 * 24 * sizeof(float), stream);

    k_h1<<<16, 256, 0, stream>>>(x, lW1, lb1, ws_h1);
    k_par1<<<dim3(64, 125), 256, 0, stream>>>(flips, ws_pb, ws_ct);
    k_par2<<<1, 64, 0, stream>>>(ws_ct, ws_cp);
    k_gemm<<<1001, 256, 0, stream>>>(lW2, lb2, ws_h1, edc, ws_e1d);
    k_reduce<<<dim3(64, 32), 256, 0, stream>>>(edc, ws_sums);
    k_mlp<<<64, 64, 0, stream>>>(x, ws_sums, eW1, eb1, eW2, eb2, dW1, db1, dW2, db2,
                                 aW1, ab1, aW2, ab2, bW1, bb1, bW2, bb2, olk, oa, ob);
    k_conv<<<dim3(64, 8), 256, 0, stream>>>(ws_e1d, lkk, eg, ws_pb, ws_cp, rir);
}

// Round 9
// 175.777 us; speedup vs baseline: 2.6252x; 2.6252x over previous
//
#include <hip/hip_runtime.h>
#include <hip/hip_bf16.h>

#define LJ 256008       // T*BANDS
#define TN 32001
#define OUT_LEN 32000

__device__ __forceinline__ int swz(int u) { return u ^ (((u >> 4) & 7) << 2); }

// ---------------- h1 = relu(x @ lstm_W1 + b1), stored [i][b] (f32) ----------------
__global__ __launch_bounds__(256) void k_h1(const float* __restrict__ x,
                                            const float* __restrict__ W1,
                                            const float* __restrict__ b1,
                                            float* __restrict__ h1)
{
    int idx = blockIdx.x * 256 + threadIdx.x;   // 4096 outputs
    if (idx >= 4096) return;
    int b = idx >> 6, i = idx & 63;
    float acc = b1[i];
    #pragma unroll
    for (int f = 0; f < 16; ++f)
        acc += x[b * 16 + f] * W1[f * 64 + i];
    h1[i * 64 + b] = fmaxf(acc, 0.f);
}

// -------- big GEMM: edc_pred = h1 @ W2 + b2 (f32 out) + fused exact-f32 band-mean -> edc1d ----
__global__ __launch_bounds__(256) void k_gemm(const float* __restrict__ W2,
                                              const float* __restrict__ b2,
                                              const float* __restrict__ h1,
                                              float* __restrict__ edc,
                                              float* __restrict__ edc1d)
{
    __shared__ float h1s[4096];
    int tid = threadIdx.x;
    for (int r = tid; r < 4096; r += 256) h1s[r] = h1[r];
    __syncthreads();
    int lane = tid & 63, bg = tid >> 6;          // wave-uniform bg
    long jb = (long)blockIdx.x * 256 + lane;     // this thread's columns: jb + 64*c
    float acc[4][16];
    #pragma unroll
    for (int c = 0; c < 4; ++c)
        #pragma unroll
        for (int b = 0; b < 16; ++b) acc[c][b] = 0.f;
    bool a0 = jb < LJ, a1 = jb + 64 < LJ, a2 = jb + 128 < LJ, a3 = jb + 192 < LJ;
    for (int i = 0; i < 64; ++i) {
        const float* wr = W2 + (long)i * LJ + jb;
        float w0 = a0 ? wr[0]   : 0.f;
        float w1 = a1 ? wr[64]  : 0.f;
        float w2 = a2 ? wr[128] : 0.f;
        float w3 = a3 ? wr[192] : 0.f;
        const float4* hv = (const float4*)(h1s + i * 64 + bg * 16);
        #pragma unroll
        for (int b4 = 0; b4 < 4; ++b4) {
            float4 h4 = hv[b4];
            acc[0][b4*4+0] += h4.x * w0; acc[0][b4*4+1] += h4.y * w0;
            acc[0][b4*4+2] += h4.z * w0; acc[0][b4*4+3] += h4.w * w0;
            acc[1][b4*4+0] += h4.x * w1; acc[1][b4*4+1] += h4.y * w1;
            acc[1][b4*4+2] += h4.z * w1; acc[1][b4*4+3] += h4.w * w1;
            acc[2][b4*4+0] += h4.x * w2; acc[2][b4*4+1] += h4.y * w2;
            acc[2][b4*4+2] += h4.z * w2; acc[2][b4*4+3] += h4.w * w2;
            acc[3][b4*4+0] += h4.x * w3; acc[3][b4*4+1] += h4.y * w3;
            acc[3][b4*4+2] += h4.z * w3; acc[3][b4*4+3] += h4.w * w3;
        }
    }
    int bgbase = bg * 16;
    #pragma unroll
    for (int c = 0; c < 4; ++c) {
        long j = jb + 64 * c;
        if (j < LJ) {               // 8-lane groups never split here (LJ % 8 == 0)
            float bias = b2[j];
            int t = (int)(j >> 3), band = (int)(j & 7);
            #pragma unroll
            for (int b = 0; b < 16; ++b) {
                float v = acc[c][b] + bias;
                edc[(long)(bgbase + b) * LJ + j] = v;
                float s = v;
                s += __shfl_xor(s, 1);
                s += __shfl_xor(s, 2);
                s += __shfl_xor(s, 4);
                if (band == 0) edc1d[(long)(bgbase + b) * TN + t] = s * 0.125f;
            }
        }
    }
}

// ---------------- time/quartile means of edc_pred -> sums[b][band][{all,q1,q4}] ----------------
__global__ __launch_bounds__(256) void k_reduce(const float* __restrict__ edc,
                                                float* __restrict__ sums)
{
    int b = blockIdx.x, c = blockIdx.y, tid = threadIdx.x;
    float sA = 0.f, s1 = 0.f, s4 = 0.f;
    for (int it = 0; it < 32; ++it) {
        int jl = c * 8192 + tid + it * 256;           // band = tid&7 invariant
        if (jl < LJ) {
            float v = edc[(long)b * LJ + jl];
            int t = jl >> 3;
            sA += v;
            if (t < 8000) s1 += v;
            if (t >= 24000) s4 += v;
        }
    }
    __shared__ float red[768];
    red[tid] = sA; red[tid + 256] = s1; red[tid + 512] = s4;
    __syncthreads();
    #pragma unroll
    for (int off = 128; off >= 8; off >>= 1) {
        if (tid < off) {
            red[tid] += red[tid + off];
            red[tid + 256] += red[tid + 256 + off];
            red[tid + 512] += red[tid + 512 + off];
        }
        __syncthreads();
    }
    if (tid < 8) {
        atomicAdd(&sums[b * 24 + tid * 3 + 0], red[tid]);
        atomicAdd(&sums[b * 24 + tid * 3 + 1], red[tid + 256]);
        atomicAdd(&sums[b * 24 + tid * 3 + 2], red[tid + 512]);
    }
}

// ---------------- small MLP head: one block per batch row, f32 outputs ----------------
__global__ __launch_bounds__(64) void k_mlp(const float* __restrict__ x,
    const float* __restrict__ sums,
    const float* __restrict__ eW1, const float* __restrict__ eb1,
    const float* __restrict__ eW2, const float* __restrict__ eb2,
    const float* __restrict__ dW1, const float* __restrict__ db1,
    const float* __restrict__ dW2, const float* __restrict__ db2,
    const float* __restrict__ aW1, const float* __restrict__ ab1,
    const float* __restrict__ aW2, const float* __restrict__ ab2,
    const float* __restrict__ bW1, const float* __restrict__ bb1,
    const float* __restrict__ bW2, const float* __restrict__ bb2,
    float* __restrict__ out_lk, float* __restrict__ out_a, float* __restrict__ out_b)
{
    int b = blockIdx.x, o = threadIdx.x;
    __shared__ float feat[16], a1[64], hh[64], t1[64];
    if (o < 16) {
        float v;
        if (o < 8) v = sums[b * 24 + o * 3] * (1.f / 32001.f);
        else {
            int band = o - 8;
            v = sums[b * 24 + band * 3 + 2] * (1.f / 8001.f)
              - sums[b * 24 + band * 3 + 1] * (1.f / 8000.f);
        }
        feat[o] = v;
    }
    __syncthreads();
    {   float acc = eb1[o];
        #pragma unroll
        for (int c = 0; c < 16; ++c) acc += feat[c] * eW1[c * 64 + o];
        a1[o] = fmaxf(acc, 0.f); }
    __syncthreads();
    {   float acc = eb2[o];
        for (int c = 0; c < 64; ++c) acc += a1[c] * eW2[c * 64 + o];
        hh[o] = fmaxf(acc, 0.f); }
    __syncthreads();
    {   float acc = db1[o];
        #pragma unroll
        for (int c = 0; c < 3; ++c) acc += x[b * 16 + c] * dW1[c * 64 + o];
        for (int c = 0; c < 64; ++c) acc += hh[c] * dW1[(3 + c) * 64 + o];
        t1[o] = fmaxf(acc, 0.f); }
    __syncthreads();
    if (o < 16) {
        float acc = db2[o];
        for (int c = 0; c < 64; ++c) acc += t1[c] * dW2[c * 16 + o];
        out_lk[b * 16 + o] = acc;
    }
    __syncthreads();
    if (o < 32) {
        float acc = ab1[o];
        for (int c = 0; c < 64; ++c) acc += hh[c] * aW1[c * 32 + o];
        t1[o] = fmaxf(acc, 0.f);
    }
    __syncthreads();
    if (o < 16) {
        float acc = ab2[o];
        for (int c = 0; c < 32; ++c) acc += t1[c] * aW2[c * 16 + o];
        out_a[b * 16 + o] = acc;
    }
    __syncthreads();
    if (o < 32) {
        float acc = bb1[o];
        for (int c = 0; c < 64; ++c) acc += hh[c] * bW1[c * 32 + o];
        t1[o] = fmaxf(acc, 0.f);
    }
    __syncthreads();
    if (o < 16) {
        float acc = bb2[o];
        for (int c = 0; c < 32; ++c) acc += t1[c] * bW2[c * 16 + o];
        out_b[b * 16 + o] = acc;
    }
}

// ---------------- parity stage 1: packed bits (per-(b, 256-chunk) inclusive XOR scan) ----------
__global__ __launch_bounds__(256) void k_par1(const int* __restrict__ flips,
                                              unsigned* __restrict__ parbits,
                                              unsigned* __restrict__ ctot)
{
    int b = blockIdx.x, c = blockIdx.y, tid = threadIdx.x;
    int t = c * 256 + tid;
    int bit = (t == 0) ? 0 : (flips[(long)b * OUT_LEN + t] & 1);
    int lane = tid & 63, wv = tid >> 6;
    unsigned long long mask = __ballot(bit != 0);
    int below = ((int)__popcll(mask & ((1ull << lane) - 1ull))) & 1;
    int incl = below ^ bit;
    __shared__ int wtot[4];
    if (lane == 0) wtot[wv] = ((int)__popcll(mask)) & 1;
    __syncthreads();
    int pre = 0;
    for (int w = 0; w < wv; ++w) pre ^= wtot[w];
    int inclB = pre ^ incl;
    unsigned long long m2 = __ballot(inclB != 0);
    if (lane == 0)  parbits[b * 1000 + c * 8 + wv * 2 + 0] = (unsigned)(m2 & 0xffffffffull);
    if (lane == 32) parbits[b * 1000 + c * 8 + wv * 2 + 1] = (unsigned)(m2 >> 32);
    if (tid == 0) ctot[c * 64 + b] = (unsigned)(wtot[0] ^ wtot[1] ^ wtot[2] ^ wtot[3]);
}

// ---------------- parity stage 2: exclusive prefix over chunks ----------------
__global__ __launch_bounds__(64) void k_par2(const unsigned* __restrict__ ctot,
                                             unsigned* __restrict__ cpref)
{
    int b = threadIdx.x;
    unsigned carry = 0;
    for (int c = 0; c < 125; ++c) {
        cpref[c * 64 + b] = carry;
        carry ^= ctot[c * 64 + b];
    }
}

// ------- conv (late+early) + amp + sign -> rir; XOR-swizzled LDS window, 16-tap blocks ---------
__global__ __launch_bounds__(128) void k_conv(const float* __restrict__ edc1d,
    const float* __restrict__ lk, const float* __restrict__ eg,
    const unsigned* __restrict__ parbits, const unsigned* __restrict__ cpref,
    float* __restrict__ rir)
{
    __shared__ __align__(16) float ker[1024];
    __shared__ __align__(16) float sw[3104];     // 3073 used; swizzle permutes within 32-float wins
    int b = blockIdx.x, t0 = blockIdx.y * 2048, tid = threadIdx.x;
    for (int k = tid; k < 1024; k += 128) {
        float g = lk[k];
        if (k < 43) g += eg[k];                   // early+late = one conv
        ker[k] = g;
    }
    const float* src = edc1d + (long)b * TN;
    for (int u = tid; u < 3073; u += 128) {
        int gt = t0 - 1024 + u;
        float v = (gt >= 0 && gt <= OUT_LEN) ? src[gt] : 0.f;
        sw[swz(u)] = v;
    }
    __syncthreads();
    int lt = tid * 16;
    int t = t0 + lt;
    if (t >= OUT_LEN) return;
    float acc[16];
    #pragma unroll
    for (int d = 0; d < 16; ++d) acc[d] = 0.f;
    for (int k16 = 0; k16 < 1024; k16 += 16) {
        const float4* gp = (const float4*)(ker + k16);
        float4 g0 = gp[0], g1 = gp[1], g2 = gp[2], g3 = gp[3];
        float g[16] = {g0.x,g0.y,g0.z,g0.w, g1.x,g1.y,g1.z,g1.w,
                       g2.x,g2.y,g2.z,g2.w, g3.x,g3.y,g3.z,g3.w};
        int ch0 = (lt + 1024 - k16 - 16) >> 2;    // 16-float-aligned window base chunk
        float w2[32];
        #pragma unroll
        for (int s = 0; s < 8; ++s) {
            int a = ch0 + s;
            int as = a ^ ((a >> 2) & 7);          // chunk-level swizzle == swz on floats
            float4 v = *(const float4*)(sw + 4 * as);
            w2[4*s+0] = v.x; w2[4*s+1] = v.y; w2[4*s+2] = v.z; w2[4*s+3] = v.w;
        }
        #pragma unroll
        for (int j = 0; j < 16; ++j)
            #pragma unroll
            for (int d = 0; d < 16; ++d)
                acc[d] += g[j] * w2[16 + d - j];  // w2[m] = src[t - k16 - 16 + m]
    }
    float sv[17];
    #pragma unroll
    for (int d = 0; d < 17; ++d) sv[d] = sw[swz(lt + 1024 + d)];
    unsigned pw = parbits[b * 1000 + (t >> 5)];   // all 16 t share one word (t%32 in {0,16})
    unsigned cp = cpref[(t >> 8) * 64 + b] & 1u;
    int sh = t & 31;
    float r[16];
    #pragma unroll
    for (int d = 0; d < 16; ++d) {
        float diff = sv[d] - sv[d + 1];
        float amp = diff > 0.f ? sqrtf(diff) : 0.f;
        unsigned p = ((pw >> (sh + d)) & 1u) ^ cp;
        float sgn = p ? -1.f : 1.f;
        r[d] = acc[d] * amp * sgn;
    }
    float4* dst = (float4*)(rir + (long)b * OUT_LEN + t);
    dst[0] = make_float4(r[0],  r[1],  r[2],  r[3]);
    dst[1] = make_float4(r[4],  r[5],  r[6],  r[7]);
    dst[2] = make_float4(r[8],  r[9],  r[10], r[11]);
    dst[3] = make_float4(r[12], r[13], r[14], r[15]);
}

extern "C" void kernel_launch(void* const* d_in, const int* in_sizes, int n_in,
                              void* d_out, int out_size, void* d_ws, size_t ws_size,
                              hipStream_t stream) {
    (void)in_sizes; (void)n_in; (void)out_size; (void)ws_size;
    const float* x    = (const float*)d_in[0];
    const float* lW1  = (const float*)d_in[1];  const float* lb1 = (const float*)d_in[2];
    const float* lW2  = (const float*)d_in[3];  const float* lb2 = (const float*)d_in[4];
    const float* eW1  = (const float*)d_in[5];  const float* eb1 = (const float*)d_in[6];
    const float* eW2  = (const float*)d_in[7];  const float* eb2 = (const float*)d_in[8];
    const float* dW1  = (const float*)d_in[9];  const float* db1 = (const float*)d_in[10];
    const float* dW2  = (const float*)d_in[11]; const float* db2 = (const float*)d_in[12];
    const float* aW1  = (const float*)d_in[13]; const float* ab1 = (const float*)d_in[14];
    const float* aW2  = (const float*)d_in[15]; const float* ab2 = (const float*)d_in[16];
    const float* bW1  = (const float*)d_in[17]; const float* bb1 = (const float*)d_in[18];
    const float* bW2  = (const float*)d_in[19]; const float* bb2 = (const float*)d_in[20];
    const float* eg   = (const float*)d_in[21]; const float* lkk = (const float*)d_in[22];
    const int* flips  = (const int*)d_in[23];

    float* out = (float*)d_out;                    // f32 output buffer
    float* rir = out;                              // 2,048,000
    float* edc = out + 2048000;                    // 16,384,512
    float* olk = out + 18432512;                   // 1,024
    float* oa  = out + 18433536;                   // 1,024
    float* ob  = out + 18434560;                   // 1,024

    // -------- compact ws layout (total 8,538,368 B) --------
    char* wsb = (char*)d_ws;
    float*    ws_h1   = (float*)(wsb + 1024);       // 16,384 B
    unsigned* ws_ct   = (unsigned*)(wsb + 18432);   // 32,000 B
    unsigned* ws_cp   = (unsigned*)(wsb + 50688);   // 32,000 B
    unsigned* ws_pb   = (unsigned*)(wsb + 82944);   // 256,000 B
    float*    ws_sums = (float*)(wsb + 339200);     // 6,144 B
    float*    ws_e1d  = (float*)(wsb + 346112);     // 8,192,256 B -> ends 8,538,368

    hipMemsetAsync(ws_sums, 0, 64 * 24 * sizeof(float), stream);

    k_h1<<<16, 256, 0, stream>>>(x, lW1, lb1, ws_h1);
    k_par1<<<dim3(64, 125), 256, 0, stream>>>(flips, ws_pb, ws_ct);
    k_par2<<<1, 64, 0, stream>>>(ws_ct, ws_cp);
    k_gemm<<<1001, 256, 0, stream>>>(lW2, lb2, ws_h1, edc, ws_e1d);
    k_reduce<<<dim3(64, 32), 256, 0, stream>>>(edc, ws_sums);
    k_mlp<<<64, 64, 0, stream>>>(x, ws_sums, eW1, eb1, eW2, eb2, dW1, db1, dW2, db2,
                                 aW1, ab1, aW2, ab2, bW1, bb1, bW2, bb2, olk, oa, ob);
    k_conv<<<dim3(64, 16), 128, 0, stream>>>(ws_e1d, lkk, eg, ws_pb, ws_cp, rir);
}